// Round 3
// baseline (432.915 us; speedup 1.0000x reference)
//
#include <hip/hip_runtime.h>
#include <math.h>

#define BB 512
#define HH 512
#define KK 6
#define TT 60
#define OO 2
#define H2 1024
#define TO 120
#define RFP 520   // padded LDS row stride (bf16 elems), 1040B = 65x16B
#define HSP 1032  // padded h row stride (bf16 elems)

typedef __bf16 bf16x8 __attribute__((ext_vector_type(8)));
typedef float  f32x4  __attribute__((ext_vector_type(4)));
typedef float  f32x16 __attribute__((ext_vector_type(16)));

__device__ __forceinline__ float bf2f(unsigned short u) {
    union { unsigned int i; float f; } v; v.i = ((unsigned int)u) << 16; return v.f;
}
__device__ __forceinline__ unsigned short f2bf(float f) {
    union { float f; unsigned int i; } v; v.f = f;
    unsigned int b = v.i;
    return (unsigned short)((b + 0x7FFFu + ((b >> 16) & 1u)) >> 16); // RNE
}
__device__ __forceinline__ float gelu_exact(float x) {
    return 0.5f * x * (1.0f + erff(x * 0.70710678118654752f));
}

#if defined(__has_builtin)
#  if __has_builtin(__builtin_amdgcn_rcpf)
#    define FAST_RCP(x) __builtin_amdgcn_rcpf(x)
#  endif
#  if __has_builtin(__builtin_amdgcn_exp2f)
#    define FAST_EXP2(x) __builtin_amdgcn_exp2f(x)
#  endif
#endif
#ifndef FAST_RCP
#  define FAST_RCP(x) (1.0f / (x))
#endif
#ifndef FAST_EXP2
#  define FAST_EXP2(x) __expf((x) * 0.69314718056f)
#endif

// tanh-form GELU, constants pre-scaled by log2(e); ~7 VALU inst, err ~3e-4.
__device__ __forceinline__ float gelu_cheap(float x) {
    float x2 = x * x;
    float z = x * fmaf(0.10294324f, x2, 2.3022082f);
    float e = FAST_EXP2(-z);
    return x * FAST_RCP(1.0f + e);
}

struct F8 { float v[8]; };
__device__ __forceinline__ F8 load8f(const float* p) {
    F8 r;
    float4 a = *(const float4*)p;
    float4 b = *(const float4*)(p + 4);
    r.v[0] = a.x; r.v[1] = a.y; r.v[2] = a.z; r.v[3] = a.w;
    r.v[4] = b.x; r.v[5] = b.y; r.v[6] = b.z; r.v[7] = b.w;
    return r;
}
__device__ __forceinline__ F8 load8b(const unsigned short* p) {
    ushort4 a = *(const ushort4*)p;
    ushort4 b = *(const ushort4*)(p + 4);
    F8 r;
    r.v[0] = bf2f(a.x); r.v[1] = bf2f(a.y); r.v[2] = bf2f(a.z); r.v[3] = bf2f(a.w);
    r.v[4] = bf2f(b.x); r.v[5] = bf2f(b.y); r.v[6] = bf2f(b.z); r.v[7] = bf2f(b.w);
    return r;
}

// ---- fused transpose: 8 weight tensors fp32 [F][N](xZ) -> bf16 [N][F], one launch ----
struct TD { const float* src; unsigned short* dst; int F, N, tiles; };
struct TD8 { TD e[8]; };

__global__ void k_trans_all(TD8 d) {
    __shared__ unsigned short t[32][33];
    int idx = blockIdx.x;
    int i = 0;
    while (i < 7 && idx >= d.e[i].tiles) { idx -= d.e[i].tiles; ++i; }
    const int F = d.e[i].F, N = d.e[i].N;
    const int tx = F >> 5, ty = (N + 31) >> 5;
    const int per = tx * ty;
    const int z = idx / per; idx -= z * per;
    const int fx = (idx % tx) * 32, ny = (idx / tx) * 32;
    const float* src = d.e[i].src + (size_t)z * F * N;
    unsigned short* dst = d.e[i].dst + (size_t)z * F * N;
    const int r = threadIdx.x / 32, c = threadIdx.x % 32;
#pragma unroll
    for (int q = 0; q < 4; ++q) {
        int fr = fx + r + 8 * q;
        if (ny + c < N) t[r + 8 * q][c] = f2bf(src[(size_t)fr * N + ny + c]);
    }
    __syncthreads();
#pragma unroll
    for (int q = 0; q < 4; ++q) {
        int nr = ny + r + 8 * q;
        if (nr < N) dst[(size_t)nr * F + fx + c] = t[c][r + 8 * q];
    }
}

// --------- MFMA ctx-chain GEMM: C(512x512 bf16) = [gelu](A @ B + bias) ---------
template <bool CONCAT, bool GELU>
__launch_bounds__(256)
__global__ void k_gemm_m(const void* __restrict__ A0, const void* __restrict__ A1,
                         const void* __restrict__ A2, const unsigned short* __restrict__ BT,
                         const float* __restrict__ bias, unsigned short* __restrict__ C,
                         int Kd) {
    __shared__ __align__(16) unsigned short As[32 * RFP];
    const int tid = threadIdx.x;
    const int bm = blockIdx.x * 32;
    const int bn = blockIdx.y * 64;
    const int w = tid >> 6, ln = tid & 63;
    const int lane15 = ln & 15, quad = ln >> 4;
    const int n = bn + w * 16 + lane15;
    const int nchunks = Kd / HH;

    f32x4 acc0 = {0.f, 0.f, 0.f, 0.f}, acc1 = {0.f, 0.f, 0.f, 0.f};

    for (int kc = 0; kc < nchunks; ++kc) {
        {
            int r = tid >> 3, c0 = (tid & 7) * 64;
            unsigned short* dp = As + r * RFP + c0;
            if (CONCAT) {
                const float* src = (kc == 0) ? (const float*)A0
                                 : (kc == 1) ? (const float*)A1 : (const float*)A2;
                const float* sp = src + (bm + r) * HH + c0;
                for (int c = 0; c < 64; c += 8) {
                    F8 v = load8f(sp + c);
                    unsigned int pk[4];
#pragma unroll
                    for (int j = 0; j < 4; ++j)
                        pk[j] = (unsigned int)f2bf(v.v[2 * j]) |
                                ((unsigned int)f2bf(v.v[2 * j + 1]) << 16);
                    *(uint4*)(dp + c) = make_uint4(pk[0], pk[1], pk[2], pk[3]);
                }
            } else {
                const unsigned short* sp = (const unsigned short*)A0 + (bm + r) * HH + c0;
                for (int c = 0; c < 64; c += 8)
                    *(uint4*)(dp + c) = *(const uint4*)(sp + c);
            }
        }
        __syncthreads();
        const unsigned short* bp = BT + (size_t)n * Kd + kc * HH + quad * 8;
#pragma unroll
        for (int f0 = 0; f0 < HH; f0 += 32) {
            bf16x8 a0 = *(const bf16x8*)(As + lane15 * RFP + f0 + quad * 8);
            bf16x8 a1 = *(const bf16x8*)(As + (16 + lane15) * RFP + f0 + quad * 8);
            bf16x8 bf = *(const bf16x8*)(bp + f0);
            acc0 = __builtin_amdgcn_mfma_f32_16x16x32_bf16(a0, bf, acc0, 0, 0, 0);
            acc1 = __builtin_amdgcn_mfma_f32_16x16x32_bf16(a1, bf, acc1, 0, 0, 0);
        }
        __syncthreads();
    }
    const float bb = bias[n];
#pragma unroll
    for (int reg = 0; reg < 4; ++reg) {
        float v0 = acc0[reg] + bb, v1 = acc1[reg] + bb;
        if (GELU) { v0 = gelu_exact(v0); v1 = gelu_exact(v1); }
        C[(bm + quad * 4 + reg) * HH + n] = f2bf(v0);
        C[(bm + 16 + quad * 4 + reg) * HH + n] = f2bf(v1);
    }
}

// ---------------- k_bc: batched coarse-heads + conf, per (k, 16 b-rows), 8 waves ----------------
__launch_bounds__(512)
__global__ void k_bc(const unsigned short* __restrict__ ctx, const float* __restrict__ mq,
                     const unsigned short* __restrict__ Wk1T, const float* __restrict__ bk1,
                     const unsigned short* __restrict__ Wk2T, const float* __restrict__ bk2,
                     const unsigned short* __restrict__ Wf1T, const float* __restrict__ bf1,
                     const float* __restrict__ Wf2, const float* __restrict__ bf2v,
                     unsigned short* __restrict__ coarse_out, float* __restrict__ conf_out)
{
    __shared__ __align__(16) unsigned short mf[16 * RFP];   // 16,640 B
    __shared__ __align__(16) unsigned short hs[16 * HSP];   // 33,024 B

    const int tid = threadIdx.x;
    const int k = blockIdx.x % KK;
    const int b0 = (blockIdx.x / KK) * 16;
    const int w = tid >> 6;
    const int ln = tid & 63;
    const int lane15 = ln & 15;
    const int quad = ln >> 4;

    // ---- stage mf = bf16(ctx + mq[k]) rows b0..b0+15 ----
    {
        int r = tid >> 5;               // 0..15
        int c0 = (tid & 31) * 16;
        const unsigned short* cp = ctx + (b0 + r) * HH + c0;
        const float* qp = mq + k * HH + c0;
        unsigned short* dp = mf + r * RFP + c0;
        for (int c = 0; c < 16; c += 8) {
            F8 cv = load8b(cp + c);
            F8 qv = load8f(qp + c);
            unsigned int pk[4];
#pragma unroll
            for (int j = 0; j < 4; ++j)
                pk[j] = (unsigned int)f2bf(cv.v[2 * j] + qv.v[2 * j]) |
                        ((unsigned int)f2bf(cv.v[2 * j + 1] + qv.v[2 * j + 1]) << 16);
            *(uint4*)(dp + c) = make_uint4(pk[0], pk[1], pk[2], pk[3]);
        }
    }
    __syncthreads();

    // ---- GEMM1: h = gelu(mf @ Wk1[k] + bk1[k]) -> hs. Per-wave n-slice 128. ----
    {
        const unsigned short* wk1t = Wk1T + (size_t)k * H2 * HH;
        const float* bk1p = bk1 + k * H2;
        for (int g = 0; g < 8; ++g) {
            const int n = w * 128 + g * 16 + lane15;
            f32x4 acc0 = {0.f,0.f,0.f,0.f};
            const unsigned short* bp = wk1t + (size_t)n * HH + quad * 8;
#pragma unroll
            for (int f0 = 0; f0 < HH; f0 += 32) {
                bf16x8 a0 = *(const bf16x8*)(mf + lane15 * RFP + f0 + quad * 8);
                bf16x8 bf = *(const bf16x8*)(bp + f0);
                acc0 = __builtin_amdgcn_mfma_f32_16x16x32_bf16(a0, bf, acc0, 0, 0, 0);
            }
            const float bias = bk1p[n];
#pragma unroll
            for (int reg = 0; reg < 4; ++reg)
                hs[(quad * 4 + reg) * HSP + n] = f2bf(gelu_exact(acc0[reg] + bias));
        }
    }
    __syncthreads();

    // ---- GEMM2: coarse = h @ Wk2[k] + bk2[k]. Per-wave n-tile 16. ----
    {
        const unsigned short* wk2t = Wk2T + (size_t)k * TO * H2;
        const int n = w * 16 + lane15;
        const int nc = (n < TO) ? n : (TO - 1);
        f32x4 acc0 = {0.f,0.f,0.f,0.f};
        const unsigned short* bp = wk2t + (size_t)nc * H2 + quad * 8;
#pragma unroll
        for (int f0 = 0; f0 < H2; f0 += 32) {
            bf16x8 a0 = *(const bf16x8*)(hs + lane15 * HSP + f0 + quad * 8);
            bf16x8 bf = *(const bf16x8*)(bp + f0);
            acc0 = __builtin_amdgcn_mfma_f32_16x16x32_bf16(a0, bf, acc0, 0, 0, 0);
        }
        if (n < TO) {
            const float bias = bk2[k * TO + n];
#pragma unroll
            for (int reg = 0; reg < 4; ++reg)
                coarse_out[((b0 + quad * 4 + reg) * KK + k) * TO + n] = f2bf(acc0[reg] + bias);
        }
    }

    // ---- GEMM3 (wave 0): conf = relu(mf @ Wf1 + bf1) @ Wf2 + bf2 ----
    if (w == 0) {
        f32x4 acc[4];
#pragma unroll
        for (int nt = 0; nt < 4; ++nt) { f32x4 z = {0.f,0.f,0.f,0.f}; acc[nt] = z; }
#pragma unroll
        for (int f0 = 0; f0 < HH; f0 += 32) {
            bf16x8 a0 = *(const bf16x8*)(mf + lane15 * RFP + f0 + quad * 8);
#pragma unroll
            for (int nt = 0; nt < 4; ++nt) {
                const int n = nt * 16 + lane15;
                bf16x8 bf = *(const bf16x8*)(Wf1T + (size_t)n * HH + f0 + quad * 8);
                acc[nt] = __builtin_amdgcn_mfma_f32_16x16x32_bf16(a0, bf, acc[nt], 0, 0, 0);
            }
        }
        const float b2 = bf2v[0];
#pragma unroll
        for (int reg = 0; reg < 4; ++reg) {
            float s = 0.f;
#pragma unroll
            for (int nt = 0; nt < 4; ++nt) {
                const int n = nt * 16 + lane15;
                s = fmaf(fmaxf(acc[nt][reg] + bf1[n], 0.f), Wf2[n], s);
            }
#pragma unroll
            for (int off = 1; off < 16; off <<= 1) s += __shfl_xor(s, off);
            if (lane15 == 0)
                conf_out[(b0 + quad * 4 + reg) * KK + k] = s + b2;
        }
    }
}

// ---------------- k_ef: one block per b, k-loop with E(k+1) || F(k) overlap ----------------
// Phase convoy fix: rf double-buffered; waves 0-3 run {E(k+1); F(k)}, waves 4-7 run
// {F(k); E(k+1)} so each SIMD (hosting waves s and s+4) has one VALU-issuing and one
// MFMA-issuing wave at all times (m114: separate pipes overlap fully).
__launch_bounds__(512, 2)
__global__ void k_ef(
    const unsigned short* __restrict__ attn, const unsigned short* __restrict__ coarse_ws,
    const float* __restrict__ Wt,  const float* __restrict__ bt,
    const float* __restrict__ lng, const float* __restrict__ lnb,
    const unsigned short* __restrict__ Wr1T, const float* __restrict__ br1,
    const float* __restrict__ Wr2, const float* __restrict__ br2,
    float* __restrict__ pred_out)
{
    __shared__ __align__(16) unsigned short rf[2][64 * RFP];  // 133,120 B
    __shared__ float  po2[2][8][64][2];                        // 8,192 B
    __shared__ float  br1d[2][HH];                             // 4,096 B
    __shared__ float2 wr2d[2][HH];                             // 8,192 B
    // total 153,600 B -> 1 block/CU

    const int tid = threadIdx.x;
    const int b = blockIdx.x;        // grid = BB
    const int w = tid >> 6;          // 0..7
    const int ln = tid & 63;
    const int lane31 = ln & 31;
    const int hf = ln >> 5;
    const int cbase = ln * 8;

    // ---- per-block hoisted state (shared by all 6 modes) ----
    F8 w0 = load8f(Wt + cbase);
    F8 w1 = load8f(Wt + HH + cbase);
    F8 b8 = load8f(bt + cbase);
    F8 g8 = load8f(lng + cbase);
    F8 bb8 = load8f(lnb + cbase);
    F8 a8 = load8b(attn + b * HH + cbase);

    // E: rf[buf] = LN(gelu(coarse[b,j] @ Wt + bt) + attn_b) for mode j (this wave's 8 rows)
    auto do_E = [&](int j, int buf) {
        unsigned short* rfb = &rf[buf][0];
        const unsigned short* cw = coarse_ws + (b * KK + j) * TO;
#pragma unroll
        for (int r = 0; r < 8; ++r) {
            int t = w + 8 * r;
            if (t < 60) {
                unsigned int cc = *(const unsigned int*)(cw + 2 * t);
                float co0 = bf2f((unsigned short)(cc & 0xffffu));
                float co1 = bf2f((unsigned short)(cc >> 16));
                float x[8]; float s = 0.f, s2 = 0.f;
#pragma unroll
                for (int jj = 0; jj < 8; ++jj) {
                    float vv = fmaf(co0, w0.v[jj], fmaf(co1, w1.v[jj], b8.v[jj]));
                    vv = gelu_cheap(vv) + a8.v[jj];
                    x[jj] = vv; s += vv; s2 = fmaf(vv, vv, s2);
                }
#pragma unroll
                for (int off = 32; off > 0; off >>= 1) {
                    s += __shfl_xor(s, off);
                    s2 += __shfl_xor(s2, off);
                }
                float mean = s * (1.0f / HH);
                float var = fmaf(-mean, mean, s2 * (1.0f / HH));
                float inv = rsqrtf(var + 1e-5f);
                unsigned int pk[4];
#pragma unroll
                for (int jj = 0; jj < 4; ++jj) {
                    float y0 = fmaf((x[2 * jj] - mean) * inv, g8.v[2 * jj], bb8.v[2 * jj]);
                    float y1 = fmaf((x[2 * jj + 1] - mean) * inv, g8.v[2 * jj + 1], bb8.v[2 * jj + 1]);
                    pk[jj] = (unsigned int)f2bf(y0) | ((unsigned int)f2bf(y1) << 16);
                }
                *(uint4*)(rfb + t * RFP + cbase) = make_uint4(pk[0], pk[1], pk[2], pk[3]);
            } else {
                *(uint4*)(rfb + t * RFP + cbase) = make_uint4(0, 0, 0, 0);
            }
        }
    };

    // stage br1/Wr2 for mode j (called by one 4-wave group: 256 threads)
    auto do_stage_g = [&](int j, int buf) {
        int i = tid & 255;
        br1d[buf][i]        = br1[j * HH + i];
        br1d[buf][i + 256]  = br1[j * HH + i + 256];
        wr2d[buf][i]        = ((const float2*)Wr2)[(size_t)j * HH + i];
        wr2d[buf][i + 256]  = ((const float2*)Wr2)[(size_t)j * HH + i + 256];
    };

    // F: r = gelu(rf@Wr1+br1); po2[buf][w] = r @ Wr2 partials (swapped-operand MFMA:
    // m = time-step on lanes, n = Wr1 col in regs -> in-lane Wr2 contraction)
    auto do_F = [&](int kk, int buf) {
        const unsigned short* wr1t_k = Wr1T + (size_t)kk * HH * HH;
        const int n0 = w * 64;
        const unsigned short* rfb = &rf[buf][0];
        const unsigned short* a0p = rfb + lane31 * RFP + hf * 8;
        const unsigned short* a1p = a0p + 32 * RFP;
        const unsigned short* b0p = wr1t_k + (size_t)(n0 + lane31) * HH + hf * 8;
        const unsigned short* b1p = b0p + (size_t)32 * HH;

        f32x16 acc00 = {0.f,0.f,0.f,0.f,0.f,0.f,0.f,0.f,0.f,0.f,0.f,0.f,0.f,0.f,0.f,0.f};
        f32x16 acc01 = acc00, acc10 = acc00, acc11 = acc00;

        __builtin_amdgcn_s_setprio(1);
#pragma unroll
        for (int k0 = 0; k0 < HH; k0 += 16) {
            bf16x8 A0 = *(const bf16x8*)(a0p + k0);
            bf16x8 A1 = *(const bf16x8*)(a1p + k0);
            bf16x8 B0 = *(const bf16x8*)(b0p + k0);
            bf16x8 B1 = *(const bf16x8*)(b1p + k0);
            acc00 = __builtin_amdgcn_mfma_f32_32x32x16_bf16(B0, A0, acc00, 0, 0, 0);
            acc01 = __builtin_amdgcn_mfma_f32_32x32x16_bf16(B1, A0, acc01, 0, 0, 0);
            acc10 = __builtin_amdgcn_mfma_f32_32x32x16_bf16(B0, A1, acc10, 0, 0, 0);
            acc11 = __builtin_amdgcn_mfma_f32_32x32x16_bf16(B1, A1, acc11, 0, 0, 0);
        }
        __builtin_amdgcn_s_setprio(0);

        float p00 = 0.f, p01 = 0.f, p10 = 0.f, p11 = 0.f;  // [m-half][o]
#pragma unroll
        for (int nt = 0; nt < 2; ++nt) {
#pragma unroll
            for (int reg = 0; reg < 16; ++reg) {
                const int n = n0 + nt * 32 + (reg & 3) + 8 * (reg >> 2) + 4 * hf;
                const float bb = br1d[buf][n];
                const float2 w2 = wr2d[buf][n];
                const float a0v = nt ? acc01[reg] : acc00[reg];
                const float a1v = nt ? acc11[reg] : acc10[reg];
                const float rv0 = gelu_cheap(a0v + bb);
                const float rv1 = gelu_cheap(a1v + bb);
                p00 = fmaf(rv0, w2.x, p00);
                p01 = fmaf(rv0, w2.y, p01);
                p10 = fmaf(rv1, w2.x, p10);
                p11 = fmaf(rv1, w2.y, p11);
            }
        }
        p00 += __shfl_xor(p00, 32);
        p01 += __shfl_xor(p01, 32);
        p10 += __shfl_xor(p10, 32);
        p11 += __shfl_xor(p11, 32);
        if (ln < 32) {
            *(float2*)&po2[buf][w][lane31][0]      = make_float2(p00, p01);
            *(float2*)&po2[buf][w][32 + lane31][0] = make_float2(p10, p11);
        }
    };

    auto do_pred = [&](int kk, int buf) {
        if (tid < TO) {
            int t = tid >> 1, o = tid & 1;
            float s = 0.f;
#pragma unroll
            for (int ww = 0; ww < 8; ++ww) s += po2[buf][ww][t][o];
            float co = bf2f(coarse_ws[(b * KK + kk) * TO + tid]);
            pred_out[((b * KK + kk) * TT + t) * 2 + o] = co + s + br2[kk * 2 + o];
        }
    };

    // ---- prologue: stage + E for mode 0 ----
    {
        br1d[0][tid] = br1[tid];
        wr2d[0][tid] = ((const float2*)Wr2)[tid];
        do_E(0, 0);
    }
    __syncthreads();

    // ---- k-loop: F(kk) on rf[cur] while E(kk+1) fills rf[cur^1] ----
    for (int kk = 0; kk < KK; ++kk) {
        const int cur = kk & 1;
        if (w < 4) {
            if (kk < KK - 1) { do_stage_g(kk + 1, cur ^ 1); do_E(kk + 1, cur ^ 1); }
            do_F(kk, cur);
        } else {
            do_F(kk, cur);
            if (kk < KK - 1) do_E(kk + 1, cur ^ 1);
        }
        __syncthreads();
        do_pred(kk, cur);
    }
}

// ---------------- softmax over K for mode_probs ----------------
__global__ void k_softmax(const float* __restrict__ conf, float* __restrict__ out) {
    int b = blockIdx.x * blockDim.x + threadIdx.x;
    if (b < BB) {
        float v[KK];
        float m = -1e30f;
        for (int i = 0; i < KK; ++i) { v[i] = conf[b * KK + i]; m = fmaxf(m, v[i]); }
        float s = 0.f;
        for (int i = 0; i < KK; ++i) { v[i] = __expf(v[i] - m); s += v[i]; }
        float inv = 1.0f / s;
        for (int i = 0; i < KK; ++i) out[b * KK + i] = v[i] * inv;
    }
}

extern "C" void kernel_launch(void* const* d_in, const int* in_sizes, int n_in,
                              void* d_out, int out_size, void* d_ws, size_t ws_size,
                              hipStream_t stream) {
    const float* I0  = (const float*)d_in[0];
    const float* I1  = (const float*)d_in[1];
    const float* I2  = (const float*)d_in[2];
    const float* MQ  = (const float*)d_in[3];
    const float* Wc1 = (const float*)d_in[4];
    const float* bc1 = (const float*)d_in[5];
    const float* Wc2 = (const float*)d_in[6];
    const float* bc2 = (const float*)d_in[7];
    const float* Wk1 = (const float*)d_in[8];
    const float* bk1 = (const float*)d_in[9];
    const float* Wk2 = (const float*)d_in[10];
    const float* bk2 = (const float*)d_in[11];
    const float* Wt  = (const float*)d_in[12];
    const float* bt  = (const float*)d_in[13];
    const float* Wv  = (const float*)d_in[18];
    const float* bv  = (const float*)d_in[19];
    const float* Wo  = (const float*)d_in[20];
    const float* bo  = (const float*)d_in[21];
    const float* lng = (const float*)d_in[22];
    const float* lnb = (const float*)d_in[23];
    const float* Wr1 = (const float*)d_in[24];
    const float* br1 = (const float*)d_in[25];
    const float* Wr2 = (const float*)d_in[26];
    const float* br2 = (const float*)d_in[27];
    const float* Wf1 = (const float*)d_in[28];
    const float* bf1 = (const float*)d_in[29];
    const float* Wf2 = (const float*)d_in[30];
    const float* bf2v = (const float*)d_in[31];

    unsigned short* wsu   = (unsigned short*)d_ws;
    unsigned short* wc1t  = wsu;                 // 786,432   [512][1536]
    unsigned short* wc2t  = wsu + 786432;        // 262,144
    unsigned short* wvt   = wsu + 1048576;       // 262,144
    unsigned short* wot   = wsu + 1310720;       // 262,144
    unsigned short* wk1t  = wsu + 1572864;       // 3,145,728 (K)[1024][512]
    unsigned short* wk2t  = wsu + 4718592;       // 737,280   (K)[120][1024]
    unsigned short* wf1t  = wsu + 5455872;       // 32,768    [64][512]
    unsigned short* wr1t  = wsu + 5488640;       // 1,572,864 (K)[512][512]
    unsigned short* ctx   = wsu + 7061504;       // 262,144
    unsigned short* attn  = wsu + 7323648;       // 262,144
    unsigned short* tmp   = wsu + 7585792;       // 262,144 (g1 / vbuf)
    unsigned short* coarse= wsu + 7847936;       // 368,640 (B,K,120)
    float* conf = (float*)(wsu + 8216576);       // 3072 fp32

    float* pred = (float*)d_out;
    float* probs = pred + BB * KK * TT * OO;

    // -- prep: all weights -> bf16 [n][f], single launch --
    TD8 td;
    td.e[0] = {Wc1, wc1t, 3 * HH, HH, 768};
    td.e[1] = {Wc2, wc2t, HH, HH, 256};
    td.e[2] = {Wv,  wvt,  HH, HH, 256};
    td.e[3] = {Wo,  wot,  HH, HH, 256};
    td.e[4] = {Wk1, wk1t, HH, H2, 3072};
    td.e[5] = {Wk2, wk2t, H2, TO, 768};
    td.e[6] = {Wf1, wf1t, HH, 64, 32};
    td.e[7] = {Wr1, wr1t, HH, HH, 1536};
    k_trans_all<<<dim3(6944), 256, 0, stream>>>(td);

    // -- ctx chain --
    k_gemm_m<true,  true ><<<dim3(16, 8), 256, 0, stream>>>(I0, I1, I2, wc1t, bc1, tmp, 3 * HH);
    k_gemm_m<false, false><<<dim3(16, 8), 256, 0, stream>>>(tmp, nullptr, nullptr, wc2t, bc2, ctx, HH);
    k_gemm_m<false, false><<<dim3(16, 8), 256, 0, stream>>>(ctx, nullptr, nullptr, wvt, bv, tmp, HH);
    k_gemm_m<false, false><<<dim3(16, 8), 256, 0, stream>>>(tmp, nullptr, nullptr, wot, bo, attn, HH);

    k_bc<<<dim3(192), 512, 0, stream>>>(ctx, MQ, wk1t, bk1, wk2t, bk2, wf1t, bf1, Wf2, bf2v,
                                        coarse, conf);
    k_ef<<<dim3(BB), 512, 0, stream>>>(attn, coarse, Wt, bt, lng, lnb,
                                       wr1t, br1, Wr2, br2, pred);
    k_softmax<<<dim3(2), 256, 0, stream>>>(conf, probs);
}

// Round 4
// 352.821 us; speedup vs baseline: 1.2270x; 1.2270x over previous
//
#include <hip/hip_runtime.h>
#include <math.h>

#define BB 512
#define HH 512
#define KK 6
#define TT 60
#define OO 2
#define H2 1024
#define TO 120
#define RFP 520   // padded LDS row stride (bf16 elems), 1040B = 65x16B
#define HSP 1032  // padded h row stride (bf16 elems)

typedef __bf16 bf16x8 __attribute__((ext_vector_type(8)));
typedef float  f32x4  __attribute__((ext_vector_type(4)));
typedef float  f32x16 __attribute__((ext_vector_type(16)));

__device__ __forceinline__ float bf2f(unsigned short u) {
    union { unsigned int i; float f; } v; v.i = ((unsigned int)u) << 16; return v.f;
}
__device__ __forceinline__ unsigned short f2bf(float f) {
    union { float f; unsigned int i; } v; v.f = f;
    unsigned int b = v.i;
    return (unsigned short)((b + 0x7FFFu + ((b >> 16) & 1u)) >> 16); // RNE
}
__device__ __forceinline__ float gelu_exact(float x) {
    return 0.5f * x * (1.0f + erff(x * 0.70710678118654752f));
}

#if defined(__has_builtin)
#  if __has_builtin(__builtin_amdgcn_rcpf)
#    define FAST_RCP(x) __builtin_amdgcn_rcpf(x)
#  endif
#  if __has_builtin(__builtin_amdgcn_exp2f)
#    define FAST_EXP2(x) __builtin_amdgcn_exp2f(x)
#  endif
#endif
#ifndef FAST_RCP
#  define FAST_RCP(x) (1.0f / (x))
#endif
#ifndef FAST_EXP2
#  define FAST_EXP2(x) __expf((x) * 0.69314718056f)
#endif

// tanh-form GELU, constants pre-scaled by log2(e); ~7 VALU inst, err ~3e-4.
__device__ __forceinline__ float gelu_cheap(float x) {
    float x2 = x * x;
    float z = x * fmaf(0.10294324f, x2, 2.3022082f);
    float e = FAST_EXP2(-z);
    return x * FAST_RCP(1.0f + e);
}

struct F8 { float v[8]; };
__device__ __forceinline__ F8 load8f(const float* p) {
    F8 r;
    float4 a = *(const float4*)p;
    float4 b = *(const float4*)(p + 4);
    r.v[0] = a.x; r.v[1] = a.y; r.v[2] = a.z; r.v[3] = a.w;
    r.v[4] = b.x; r.v[5] = b.y; r.v[6] = b.z; r.v[7] = b.w;
    return r;
}
__device__ __forceinline__ F8 load8b(const unsigned short* p) {
    ushort4 a = *(const ushort4*)p;
    ushort4 b = *(const ushort4*)(p + 4);
    F8 r;
    r.v[0] = bf2f(a.x); r.v[1] = bf2f(a.y); r.v[2] = bf2f(a.z); r.v[3] = bf2f(a.w);
    r.v[4] = bf2f(b.x); r.v[5] = bf2f(b.y); r.v[6] = bf2f(b.z); r.v[7] = bf2f(b.w);
    return r;
}

// ---- fragment-order weight pack: B-records of 512 bf16 (1KB), one wave-load each ----
// NC=16 (16x16x32 MFMA): rec[ln*8+j] = W[step*32 + (ln>>4)*8 + j][nch*16 + (ln&15)]
// NC=32 (32x32x16 MFMA): rec[ln*8+j] = W[step*16 + (ln>>5)*8 + j][nch*32 + (ln&31)]
// -> consumer load: base + (nch*steps + step)*512 + ln*8  (coalesced 1KB/wave)
struct PKD { const float* src; unsigned short* dst; int F, N, NC, nch, steps, Z; };
struct PK8 { PKD e[8]; };

__global__ void k_pack(PK8 d) {
    int rid = blockIdx.x * 4 + (threadIdx.x >> 6);
    const int ln = threadIdx.x & 63;
    int i = 0;
    while (i < 7) {
        int tot = d.e[i].Z * d.e[i].nch * d.e[i].steps;
        if (rid < tot) break;
        rid -= tot; ++i;
    }
    const PKD e = d.e[i];
    const int per = e.nch * e.steps;
    const int z = rid / per;
    const int r = rid - z * per;
    const int nch = r / e.steps, step = r - nch * e.steps;
    const float* src = e.src + (size_t)z * e.F * e.N;
    unsigned short* dst = e.dst + ((size_t)z * per + r) * 512 + ln * 8;
    int f_base, n;
    if (e.NC == 16) { f_base = step * 32 + (ln >> 4) * 8; n = nch * 16 + (ln & 15); }
    else            { f_base = step * 16 + (ln >> 5) * 8; n = nch * 32 + (ln & 31); }
    if (n >= e.N) n = e.N - 1;   // clamp (Wk2: logical 128 cols over 120 real)
    unsigned int pk[4];
#pragma unroll
    for (int j = 0; j < 4; ++j) {
        unsigned short lo = f2bf(src[(size_t)(f_base + 2 * j) * e.N + n]);
        unsigned short hi = f2bf(src[(size_t)(f_base + 2 * j + 1) * e.N + n]);
        pk[j] = (unsigned int)lo | ((unsigned int)hi << 16);
    }
    *(uint4*)dst = make_uint4(pk[0], pk[1], pk[2], pk[3]);
}

// --------- MFMA ctx-chain GEMM: C(512x512 bf16) = [gelu](A @ B + bias), packed-B ---------
template <bool CONCAT, bool GELU>
__launch_bounds__(256)
__global__ void k_gemm_m(const void* __restrict__ A0, const void* __restrict__ A1,
                         const void* __restrict__ A2, const unsigned short* __restrict__ BP,
                         const float* __restrict__ bias, unsigned short* __restrict__ C,
                         int Kd) {
    __shared__ __align__(16) unsigned short As[32 * RFP];
    const int tid = threadIdx.x;
    const int bm = blockIdx.x * 32;
    const int bn = blockIdx.y * 64;
    const int w = tid >> 6, ln = tid & 63;
    const int lane15 = ln & 15, quad = ln >> 4;
    const int n = bn + w * 16 + lane15;
    const int nchunks = Kd / HH;
    const int stepsTot = Kd / 32;
    const int nchB = blockIdx.y * 4 + w;

    f32x4 acc0 = {0.f, 0.f, 0.f, 0.f}, acc1 = {0.f, 0.f, 0.f, 0.f};

    for (int kc = 0; kc < nchunks; ++kc) {
        {
            int r = tid >> 3, c0 = (tid & 7) * 64;
            unsigned short* dp = As + r * RFP + c0;
            if (CONCAT) {
                const float* src = (kc == 0) ? (const float*)A0
                                 : (kc == 1) ? (const float*)A1 : (const float*)A2;
                const float* sp = src + (bm + r) * HH + c0;
                for (int c = 0; c < 64; c += 8) {
                    F8 v = load8f(sp + c);
                    unsigned int pk[4];
#pragma unroll
                    for (int j = 0; j < 4; ++j)
                        pk[j] = (unsigned int)f2bf(v.v[2 * j]) |
                                ((unsigned int)f2bf(v.v[2 * j + 1]) << 16);
                    *(uint4*)(dp + c) = make_uint4(pk[0], pk[1], pk[2], pk[3]);
                }
            } else {
                const unsigned short* sp = (const unsigned short*)A0 + (bm + r) * HH + c0;
                for (int c = 0; c < 64; c += 8)
                    *(uint4*)(dp + c) = *(const uint4*)(sp + c);
            }
        }
        __syncthreads();
        const unsigned short* bp = BP + ((size_t)nchB * stepsTot + kc * 16) * 512 + ln * 8;
#pragma unroll
        for (int f0 = 0; f0 < HH; f0 += 32) {
            bf16x8 a0 = *(const bf16x8*)(As + lane15 * RFP + f0 + quad * 8);
            bf16x8 a1 = *(const bf16x8*)(As + (16 + lane15) * RFP + f0 + quad * 8);
            bf16x8 bf = *(const bf16x8*)(bp);
            bp += 512;
            acc0 = __builtin_amdgcn_mfma_f32_16x16x32_bf16(a0, bf, acc0, 0, 0, 0);
            acc1 = __builtin_amdgcn_mfma_f32_16x16x32_bf16(a1, bf, acc1, 0, 0, 0);
        }
        __syncthreads();
    }
    const float bb = bias[n];
#pragma unroll
    for (int reg = 0; reg < 4; ++reg) {
        float v0 = acc0[reg] + bb, v1 = acc1[reg] + bb;
        if (GELU) { v0 = gelu_exact(v0); v1 = gelu_exact(v1); }
        C[(bm + quad * 4 + reg) * HH + n] = f2bf(v0);
        C[(bm + 16 + quad * 4 + reg) * HH + n] = f2bf(v1);
    }
}

// ---------------- k_bc: batched coarse-heads + conf, packed-B ----------------
__launch_bounds__(512)
__global__ void k_bc(const unsigned short* __restrict__ ctx, const float* __restrict__ mq,
                     const unsigned short* __restrict__ Wk1P, const float* __restrict__ bk1,
                     const unsigned short* __restrict__ Wk2P, const float* __restrict__ bk2,
                     const unsigned short* __restrict__ Wf1P, const float* __restrict__ bf1,
                     const float* __restrict__ Wf2, const float* __restrict__ bf2v,
                     unsigned short* __restrict__ coarse_out, float* __restrict__ conf_out)
{
    __shared__ __align__(16) unsigned short mf[16 * RFP];   // 16,640 B
    __shared__ __align__(16) unsigned short hs[16 * HSP];   // 33,024 B

    const int tid = threadIdx.x;
    const int k = blockIdx.x % KK;
    const int b0 = (blockIdx.x / KK) * 16;
    const int w = tid >> 6;
    const int ln = tid & 63;
    const int lane15 = ln & 15;
    const int quad = ln >> 4;

    // ---- stage mf = bf16(ctx + mq[k]) rows b0..b0+15 ----
    {
        int r = tid >> 5;               // 0..15
        int c0 = (tid & 31) * 16;
        const unsigned short* cp = ctx + (b0 + r) * HH + c0;
        const float* qp = mq + k * HH + c0;
        unsigned short* dp = mf + r * RFP + c0;
        for (int c = 0; c < 16; c += 8) {
            F8 cv = load8b(cp + c);
            F8 qv = load8f(qp + c);
            unsigned int pk[4];
#pragma unroll
            for (int j = 0; j < 4; ++j)
                pk[j] = (unsigned int)f2bf(cv.v[2 * j] + qv.v[2 * j]) |
                        ((unsigned int)f2bf(cv.v[2 * j + 1] + qv.v[2 * j + 1]) << 16);
            *(uint4*)(dp + c) = make_uint4(pk[0], pk[1], pk[2], pk[3]);
        }
    }
    __syncthreads();

    // ---- GEMM1: h = gelu(mf @ Wk1[k] + bk1[k]) -> hs. Packed-B: nch = w*8+g, 16 steps ----
    {
        const unsigned short* wk1p = Wk1P + (size_t)k * (64 * 16 * 512);
        const float* bk1p = bk1 + k * H2;
        for (int g = 0; g < 8; ++g) {
            const int n = w * 128 + g * 16 + lane15;
            f32x4 acc0 = {0.f,0.f,0.f,0.f};
            const unsigned short* bp = wk1p + (size_t)((w * 8 + g) * 16) * 512 + ln * 8;
#pragma unroll
            for (int f0 = 0; f0 < HH; f0 += 32) {
                bf16x8 a0 = *(const bf16x8*)(mf + lane15 * RFP + f0 + quad * 8);
                bf16x8 bf = *(const bf16x8*)(bp);
                bp += 512;
                acc0 = __builtin_amdgcn_mfma_f32_16x16x32_bf16(a0, bf, acc0, 0, 0, 0);
            }
            const float bias = bk1p[n];
#pragma unroll
            for (int reg = 0; reg < 4; ++reg)
                hs[(quad * 4 + reg) * HSP + n] = f2bf(gelu_exact(acc0[reg] + bias));
        }
    }
    __syncthreads();

    // ---- GEMM2: coarse = h @ Wk2[k] + bk2[k]. Packed-B: nch = w, 32 steps (clamp baked) ----
    {
        const unsigned short* wk2p = Wk2P + (size_t)k * (8 * 32 * 512);
        const int n = w * 16 + lane15;
        f32x4 acc0 = {0.f,0.f,0.f,0.f};
        const unsigned short* bp = wk2p + (size_t)(w * 32) * 512 + ln * 8;
#pragma unroll
        for (int f0 = 0; f0 < H2; f0 += 32) {
            bf16x8 a0 = *(const bf16x8*)(hs + lane15 * HSP + f0 + quad * 8);
            bf16x8 bf = *(const bf16x8*)(bp);
            bp += 512;
            acc0 = __builtin_amdgcn_mfma_f32_16x16x32_bf16(a0, bf, acc0, 0, 0, 0);
        }
        if (n < TO) {
            const float bias = bk2[k * TO + n];
#pragma unroll
            for (int reg = 0; reg < 4; ++reg)
                coarse_out[((b0 + quad * 4 + reg) * KK + k) * TO + n] = f2bf(acc0[reg] + bias);
        }
    }

    // ---- GEMM3 (wave 0): conf = relu(mf @ Wf1 + bf1) @ Wf2 + bf2. Packed-B: nch = nt ----
    if (w == 0) {
        f32x4 acc[4];
#pragma unroll
        for (int nt = 0; nt < 4; ++nt) { f32x4 z = {0.f,0.f,0.f,0.f}; acc[nt] = z; }
#pragma unroll
        for (int f0 = 0; f0 < HH; f0 += 32) {
            const int step = f0 >> 5;
            bf16x8 a0 = *(const bf16x8*)(mf + lane15 * RFP + f0 + quad * 8);
#pragma unroll
            for (int nt = 0; nt < 4; ++nt) {
                bf16x8 bf = *(const bf16x8*)(Wf1P + (size_t)(nt * 16 + step) * 512 + ln * 8);
                acc[nt] = __builtin_amdgcn_mfma_f32_16x16x32_bf16(a0, bf, acc[nt], 0, 0, 0);
            }
        }
        const float b2 = bf2v[0];
#pragma unroll
        for (int reg = 0; reg < 4; ++reg) {
            float s = 0.f;
#pragma unroll
            for (int nt = 0; nt < 4; ++nt) {
                const int n = nt * 16 + lane15;
                s = fmaf(fmaxf(acc[nt][reg] + bf1[n], 0.f), Wf2[n], s);
            }
#pragma unroll
            for (int off = 1; off < 16; off <<= 1) s += __shfl_xor(s, off);
            if (lane15 == 0)
                conf_out[(b0 + quad * 4 + reg) * KK + k] = s + b2;
        }
    }
}

// ---------------- k_ef: one block per b, k-loop with E(k+1) || F(k) overlap, packed-B ----------------
__launch_bounds__(512, 2)
__global__ void k_ef(
    const unsigned short* __restrict__ attn, const unsigned short* __restrict__ coarse_ws,
    const float* __restrict__ Wt,  const float* __restrict__ bt,
    const float* __restrict__ lng, const float* __restrict__ lnb,
    const unsigned short* __restrict__ Wr1P, const float* __restrict__ br1,
    const float* __restrict__ Wr2, const float* __restrict__ br2,
    float* __restrict__ pred_out)
{
    __shared__ __align__(16) unsigned short rf[2][64 * RFP];  // 133,120 B
    __shared__ float  po2[2][8][64][2];                        // 8,192 B
    __shared__ float  br1d[2][HH];                             // 4,096 B
    __shared__ float2 wr2d[2][HH];                             // 8,192 B

    const int tid = threadIdx.x;
    const int b = blockIdx.x;        // grid = BB
    const int w = tid >> 6;          // 0..7
    const int ln = tid & 63;
    const int lane31 = ln & 31;
    const int hf = ln >> 5;
    const int cbase = ln * 8;

    // ---- per-block hoisted state (shared by all 6 modes) ----
    F8 w0 = load8f(Wt + cbase);
    F8 w1 = load8f(Wt + HH + cbase);
    F8 b8 = load8f(bt + cbase);
    F8 g8 = load8f(lng + cbase);
    F8 bb8 = load8f(lnb + cbase);
    F8 a8 = load8b(attn + b * HH + cbase);

    auto do_E = [&](int j, int buf) {
        unsigned short* rfb = &rf[buf][0];
        const unsigned short* cw = coarse_ws + (b * KK + j) * TO;
#pragma unroll
        for (int r = 0; r < 8; ++r) {
            int t = w + 8 * r;
            if (t < 60) {
                unsigned int cc = *(const unsigned int*)(cw + 2 * t);
                float co0 = bf2f((unsigned short)(cc & 0xffffu));
                float co1 = bf2f((unsigned short)(cc >> 16));
                float x[8]; float s = 0.f, s2 = 0.f;
#pragma unroll
                for (int jj = 0; jj < 8; ++jj) {
                    float vv = fmaf(co0, w0.v[jj], fmaf(co1, w1.v[jj], b8.v[jj]));
                    vv = gelu_cheap(vv) + a8.v[jj];
                    x[jj] = vv; s += vv; s2 = fmaf(vv, vv, s2);
                }
#pragma unroll
                for (int off = 32; off > 0; off >>= 1) {
                    s += __shfl_xor(s, off);
                    s2 += __shfl_xor(s2, off);
                }
                float mean = s * (1.0f / HH);
                float var = fmaf(-mean, mean, s2 * (1.0f / HH));
                float inv = rsqrtf(var + 1e-5f);
                unsigned int pk[4];
#pragma unroll
                for (int jj = 0; jj < 4; ++jj) {
                    float y0 = fmaf((x[2 * jj] - mean) * inv, g8.v[2 * jj], bb8.v[2 * jj]);
                    float y1 = fmaf((x[2 * jj + 1] - mean) * inv, g8.v[2 * jj + 1], bb8.v[2 * jj + 1]);
                    pk[jj] = (unsigned int)f2bf(y0) | ((unsigned int)f2bf(y1) << 16);
                }
                *(uint4*)(rfb + t * RFP + cbase) = make_uint4(pk[0], pk[1], pk[2], pk[3]);
            } else {
                *(uint4*)(rfb + t * RFP + cbase) = make_uint4(0, 0, 0, 0);
            }
        }
    };

    auto do_stage_g = [&](int j, int buf) {
        int i = tid & 255;
        br1d[buf][i]        = br1[j * HH + i];
        br1d[buf][i + 256]  = br1[j * HH + i + 256];
        wr2d[buf][i]        = ((const float2*)Wr2)[(size_t)j * HH + i];
        wr2d[buf][i + 256]  = ((const float2*)Wr2)[(size_t)j * HH + i + 256];
    };

    // F: packed-B records [nch=16][step=32][512]; wave w owns nch 2w (B0) and 2w+1 (B1).
    auto do_F = [&](int kk, int buf) {
        const unsigned short* bp0 = Wr1P + (size_t)kk * (16 * 32 * 512)
                                  + (size_t)(w * 2) * 32 * 512 + ln * 8;
        const unsigned short* bp1 = bp0 + 32 * 512;   // next nch
        const int n0 = w * 64;
        const unsigned short* rfb = &rf[buf][0];
        const unsigned short* a0p = rfb + lane31 * RFP + hf * 8;
        const unsigned short* a1p = a0p + 32 * RFP;

        f32x16 acc00 = {0.f,0.f,0.f,0.f,0.f,0.f,0.f,0.f,0.f,0.f,0.f,0.f,0.f,0.f,0.f,0.f};
        f32x16 acc01 = acc00, acc10 = acc00, acc11 = acc00;

        __builtin_amdgcn_s_setprio(1);
#pragma unroll
        for (int st = 0; st < 32; ++st) {
            const int k0 = st * 16;
            bf16x8 A0 = *(const bf16x8*)(a0p + k0);
            bf16x8 A1 = *(const bf16x8*)(a1p + k0);
            bf16x8 B0 = *(const bf16x8*)(bp0 + st * 512);
            bf16x8 B1 = *(const bf16x8*)(bp1 + st * 512);
            acc00 = __builtin_amdgcn_mfma_f32_32x32x16_bf16(B0, A0, acc00, 0, 0, 0);
            acc01 = __builtin_amdgcn_mfma_f32_32x32x16_bf16(B1, A0, acc01, 0, 0, 0);
            acc10 = __builtin_amdgcn_mfma_f32_32x32x16_bf16(B0, A1, acc10, 0, 0, 0);
            acc11 = __builtin_amdgcn_mfma_f32_32x32x16_bf16(B1, A1, acc11, 0, 0, 0);
        }
        __builtin_amdgcn_s_setprio(0);

        float p00 = 0.f, p01 = 0.f, p10 = 0.f, p11 = 0.f;  // [m-half][o]
#pragma unroll
        for (int nt = 0; nt < 2; ++nt) {
#pragma unroll
            for (int reg = 0; reg < 16; ++reg) {
                const int n = n0 + nt * 32 + (reg & 3) + 8 * (reg >> 2) + 4 * hf;
                const float bb = br1d[buf][n];
                const float2 w2 = wr2d[buf][n];
                const float a0v = nt ? acc01[reg] : acc00[reg];
                const float a1v = nt ? acc11[reg] : acc10[reg];
                const float rv0 = gelu_cheap(a0v + bb);
                const float rv1 = gelu_cheap(a1v + bb);
                p00 = fmaf(rv0, w2.x, p00);
                p01 = fmaf(rv0, w2.y, p01);
                p10 = fmaf(rv1, w2.x, p10);
                p11 = fmaf(rv1, w2.y, p11);
            }
        }
        p00 += __shfl_xor(p00, 32);
        p01 += __shfl_xor(p01, 32);
        p10 += __shfl_xor(p10, 32);
        p11 += __shfl_xor(p11, 32);
        if (ln < 32) {
            *(float2*)&po2[buf][w][lane31][0]      = make_float2(p00, p01);
            *(float2*)&po2[buf][w][32 + lane31][0] = make_float2(p10, p11);
        }
    };

    auto do_pred = [&](int kk, int buf) {
        if (tid < TO) {
            int t = tid >> 1, o = tid & 1;
            float s = 0.f;
#pragma unroll
            for (int ww = 0; ww < 8; ++ww) s += po2[buf][ww][t][o];
            float co = bf2f(coarse_ws[(b * KK + kk) * TO + tid]);
            pred_out[((b * KK + kk) * TT + t) * 2 + o] = co + s + br2[kk * 2 + o];
        }
    };

    {
        br1d[0][tid] = br1[tid];
        wr2d[0][tid] = ((const float2*)Wr2)[tid];
        do_E(0, 0);
    }
    __syncthreads();

    for (int kk = 0; kk < KK; ++kk) {
        const int cur = kk & 1;
        if (w < 4) {
            if (kk < KK - 1) { do_stage_g(kk + 1, cur ^ 1); do_E(kk + 1, cur ^ 1); }
            do_F(kk, cur);
        } else {
            do_F(kk, cur);
            if (kk < KK - 1) do_E(kk + 1, cur ^ 1);
        }
        __syncthreads();
        do_pred(kk, cur);
    }
}

// ---------------- softmax over K for mode_probs ----------------
__global__ void k_softmax(const float* __restrict__ conf, float* __restrict__ out) {
    int b = blockIdx.x * blockDim.x + threadIdx.x;
    if (b < BB) {
        float v[KK];
        float m = -1e30f;
        for (int i = 0; i < KK; ++i) { v[i] = conf[b * KK + i]; m = fmaxf(m, v[i]); }
        float s = 0.f;
        for (int i = 0; i < KK; ++i) { v[i] = __expf(v[i] - m); s += v[i]; }
        float inv = 1.0f / s;
        for (int i = 0; i < KK; ++i) out[b * KK + i] = v[i] * inv;
    }
}

extern "C" void kernel_launch(void* const* d_in, const int* in_sizes, int n_in,
                              void* d_out, int out_size, void* d_ws, size_t ws_size,
                              hipStream_t stream) {
    const float* I0  = (const float*)d_in[0];
    const float* I1  = (const float*)d_in[1];
    const float* I2  = (const float*)d_in[2];
    const float* MQ  = (const float*)d_in[3];
    const float* Wc1 = (const float*)d_in[4];
    const float* bc1 = (const float*)d_in[5];
    const float* Wc2 = (const float*)d_in[6];
    const float* bc2 = (const float*)d_in[7];
    const float* Wk1 = (const float*)d_in[8];
    const float* bk1 = (const float*)d_in[9];
    const float* Wk2 = (const float*)d_in[10];
    const float* bk2 = (const float*)d_in[11];
    const float* Wt  = (const float*)d_in[12];
    const float* bt  = (const float*)d_in[13];
    const float* Wv  = (const float*)d_in[18];
    const float* bv  = (const float*)d_in[19];
    const float* Wo  = (const float*)d_in[20];
    const float* bo  = (const float*)d_in[21];
    const float* lng = (const float*)d_in[22];
    const float* lnb = (const float*)d_in[23];
    const float* Wr1 = (const float*)d_in[24];
    const float* br1 = (const float*)d_in[25];
    const float* Wr2 = (const float*)d_in[26];
    const float* br2 = (const float*)d_in[27];
    const float* Wf1 = (const float*)d_in[28];
    const float* bf1 = (const float*)d_in[29];
    const float* Wf2 = (const float*)d_in[30];
    const float* bf2v = (const float*)d_in[31];

    // workspace layout (bf16 elems)
    unsigned short* wsu   = (unsigned short*)d_ws;
    unsigned short* wc1p  = wsu;                 //   786,432  (32nch x 48st x 512)
    unsigned short* wc2p  = wsu + 786432;        //   262,144
    unsigned short* wvp   = wsu + 1048576;       //   262,144
    unsigned short* wop   = wsu + 1310720;       //   262,144
    unsigned short* wk1p  = wsu + 1572864;       // 3,145,728  (K x 64nch x 16st x 512)
    unsigned short* wk2p  = wsu + 4718592;       //   786,432  (K x 8nch x 32st x 512, clamped)
    unsigned short* wf1p  = wsu + 5505024;       //    32,768  (4nch x 16st x 512)
    unsigned short* wr1p  = wsu + 5537792;       // 1,572,864  (K x 16nch x 32st x 512)
    unsigned short* ctx   = wsu + 7110656;       //   262,144
    unsigned short* attn  = wsu + 7372800;       //   262,144
    unsigned short* tmp   = wsu + 7634944;       //   262,144
    unsigned short* coarse= wsu + 7897088;       //   368,640
    float* conf = (float*)(wsu + 8265728);       //     3,072 fp32

    float* pred = (float*)d_out;
    float* probs = pred + BB * KK * TT * OO;

    // -- prep: all GEMM B-weights -> bf16 fragment-order records, one launch --
    PK8 pk;
    pk.e[0] = {Wc1, wc1p, 3 * HH, HH, 16, 32, 48, 1};   // 1536 recs
    pk.e[1] = {Wc2, wc2p, HH, HH, 16, 32, 16, 1};       //  512
    pk.e[2] = {Wv,  wvp,  HH, HH, 16, 32, 16, 1};       //  512
    pk.e[3] = {Wo,  wop,  HH, HH, 16, 32, 16, 1};       //  512
    pk.e[4] = {Wk1, wk1p, HH, H2, 16, 64, 16, KK};      // 6144
    pk.e[5] = {Wk2, wk2p, H2, TO, 16, 8, 32, KK};       // 1536 (clamped cols)
    pk.e[6] = {Wf1, wf1p, HH, 64, 16, 4, 16, 1};        //   64
    pk.e[7] = {Wr1, wr1p, HH, HH, 32, 16, 32, KK};      // 3072
    // total 13,888 records; 4 records (waves) per 256-thread block
    k_pack<<<dim3(3472), 256, 0, stream>>>(pk);

    // -- ctx chain --
    k_gemm_m<true,  true ><<<dim3(16, 8), 256, 0, stream>>>(I0, I1, I2, wc1p, bc1, tmp, 3 * HH);
    k_gemm_m<false, false><<<dim3(16, 8), 256, 0, stream>>>(tmp, nullptr, nullptr, wc2p, bc2, ctx, HH);
    k_gemm_m<false, false><<<dim3(16, 8), 256, 0, stream>>>(ctx, nullptr, nullptr, wvp, bv, tmp, HH);
    k_gemm_m<false, false><<<dim3(16, 8), 256, 0, stream>>>(tmp, nullptr, nullptr, wop, bo, attn, HH);

    k_bc<<<dim3(192), 512, 0, stream>>>(ctx, MQ, wk1p, bk1, wk2p, bk2, wf1p, bf1, Wf2, bf2v,
                                        coarse, conf);
    k_ef<<<dim3(BB), 512, 0, stream>>>(attn, coarse, Wt, bt, lng, lnb,
                                       wr1p, br1, Wr2, br2, pred);
    k_softmax<<<dim3(2), 256, 0, stream>>>(conf, probs);
}